// Round 6
// baseline (307.241 us; speedup 1.0000x reference)
//
#include <hip/hip_runtime.h>

typedef _Float16 f16;
typedef _Float16 f16x4 __attribute__((ext_vector_type(4)));
typedef _Float16 f16x8 __attribute__((ext_vector_type(8)));
typedef float f32x4 __attribute__((ext_vector_type(4)));

#define SCL (1.4426950408889634f / 32.0f)   // SCALE^2 * log2(e), folded into K_aux

// ---------------- K0: staging transposes (x -> xt f16, W -> Wt f16) ---------
__global__ __launch_bounds__(256) void k_stage(const float* __restrict__ x,
    const float* __restrict__ Wq, const float* __restrict__ Wa,
    f16* __restrict__ xt, f16* __restrict__ Wt) {
  __shared__ f16 tile[64][65];
  int bx = blockIdx.x;
  int t = threadIdx.x, c = t & 63, rg = t >> 6;
  if (bx < 32) {
    int n0 = bx * 64, d0 = blockIdx.y * 64, b = blockIdx.z;
#pragma unroll
    for (int r = 0; r < 16; ++r) {
      int row = r * 4 + rg;
      tile[row][c] = (f16)x[((size_t)b * 2048 + n0 + row) * 256 + d0 + c];
    }
    __syncthreads();
#pragma unroll
    for (int r = 0; r < 16; ++r) {
      int drow = r * 4 + rg;
      xt[((size_t)b * 256 + d0 + drow) * 2048 + n0 + c] = tile[c][drow];
    }
  } else {
    int n0 = (bx - 32) * 64, k0 = blockIdx.y * 64, s = blockIdx.z;
    const float* W = s ? Wa : Wq;
    f16* dst = Wt + (size_t)s * 512 * 256;
#pragma unroll
    for (int r = 0; r < 16; ++r) {
      int krow = r * 4 + rg;
      tile[krow][c] = (f16)W[(size_t)(k0 + krow) * 768 + n0 + c];
    }
    __syncthreads();
#pragma unroll
    for (int r = 0; r < 16; ++r) {
      int nrow = r * 4 + rg;
      dst[(size_t)(n0 + nrow) * 256 + k0 + c] = tile[c][nrow];
    }
  }
}

// ---------------- K1: Q/K projections (A regs reused across 4 n-tiles) ------
// Out: Q*/K* as [b*8+h][2048][32] f16.  K_aux is prescaled by SCL.
// Grid (64 m-tiles, 2 n-halves, 2 streams) = 256 blocks -> every CU busy.
__global__ __launch_bounds__(256) void k_proj(const float* __restrict__ x,
    const float* __restrict__ af, const f16* __restrict__ Wt,
    f16* __restrict__ Qs, f16* __restrict__ Ks,
    f16* __restrict__ Qa, f16* __restrict__ Ka) {
  int mt = blockIdx.x, ny = blockIdx.y, s = blockIdx.z;
  const float* A = s ? af : x;
  const f16* W = Wt + (size_t)s * 512 * 256;
  f16* Qd = s ? Qa : Qs;
  f16* Kd = s ? Ka : Ks;
  int t = threadIdx.x, wv = t >> 6, ln = t & 63, cl = ln & 15, g = ln >> 4;
  int m0 = mt * 64;
  const float* arow = A + (size_t)(m0 + wv * 16 + cl) * 256 + g * 8;
  f16x8 a[8];
#pragma unroll
  for (int k32 = 0; k32 < 8; ++k32) {
    float4 u = *(const float4*)(arow + k32 * 32);
    float4 v = *(const float4*)(arow + k32 * 32 + 4);
    a[k32] = (f16x8){ (f16)u.x, (f16)u.y, (f16)u.z, (f16)u.w,
                      (f16)v.x, (f16)v.y, (f16)v.z, (f16)v.w };
  }
  f32x4 z4 = {0.f, 0.f, 0.f, 0.f};
#pragma unroll 1
  for (int nt = 0; nt < 4; ++nt) {
    int n0 = (ny * 4 + nt) * 64;
    f32x4 acc[4] = {z4, z4, z4, z4};
    const f16* wb = W + (size_t)n0 * 256 + g * 8;
#pragma unroll
    for (int k32 = 0; k32 < 8; ++k32)
#pragma unroll
      for (int n4 = 0; n4 < 4; ++n4) {
        f16x8 bf = *(const f16x8*)(wb + (size_t)(n4 * 16 + cl) * 256 + k32 * 32);
        acc[n4] = __builtin_amdgcn_mfma_f32_16x16x32_f16(a[k32], bf, acc[n4], 0, 0, 0);
      }
#pragma unroll
    for (int n4 = 0; n4 < 4; ++n4) {
      int c = n0 + n4 * 16 + cl;             // 0..511 (Q: 0-255, K: 256-511)
      int head = (c & 255) >> 5, d = c & 31;
      f16* dst = (c < 256) ? Qd : Kd;
      float osc = (s && (n0 + n4 * 16) >= 256) ? SCL : 1.0f;  // prescale K_aux
#pragma unroll
      for (int r = 0; r < 4; ++r) {
        int m = m0 + wv * 16 + g * 4 + r;
        int bb = m >> 11, nn = m & 2047;
        dst[(((size_t)bb * 8 + head) * 2048 + nn) * 32 + d] = (f16)(acc[n4][r] * osc);
      }
    }
  }
}

// ---------------- K2: fused dual-score flash attention ----------------------
// Round-2 proven structure. Per-row online max with +6 hysteresis overshoot
// (exact; P=exp2(s-m) fits f16, updates rare). launch_bounds(256,4) pins
// VGPR<=128 (4 waves/SIMD) -- 132 VGPRs cost 2x in round 5.
__global__ __launch_bounds__(256, 4) void k_flash(const f16* __restrict__ Qs,
    const f16* __restrict__ Ks, const f16* __restrict__ Qa,
    const f16* __restrict__ Ka, const f16* __restrict__ xt,
    float* __restrict__ out, float* __restrict__ out_cls,
    float* __restrict__ attn0, float* __restrict__ lq0) {
  __shared__ f16 KaL[2][64][40];     // pitch 80B
  __shared__ f16 KsL[2][64][40];
  __shared__ f16 PL[2][64][72];      // [q][j], pitch 144B
  __shared__ float alphaL[2][64] __attribute__((aligned(16)));
  __shared__ float lL[64];
  int qt = blockIdx.x, h = blockIdx.y, b = blockIdx.z;
  int bh = b * 8 + h;
  int t = threadIdx.x, wv = t >> 6, ln = t & 63, cl = ln & 15, g = ln >> 4;
  int qrow0 = qt * 64 + wv * 16;
  f16x8 qsf = *(const f16x8*)&Qs[((size_t)bh * 2048 + qrow0 + cl) * 32 + g * 8];
  f16x8 qaf = *(const f16x8*)&Qa[((size_t)bh * 2048 + qrow0 + cl) * 32 + g * 8];
  f32x4 z4 = {0.f, 0.f, 0.f, 0.f};
  f32x4 acc[4][4];                   // [qt2][ddt]
#pragma unroll
  for (int i = 0; i < 4; ++i)
#pragma unroll
    for (int j = 0; j < 4; ++j) acc[i][j] = z4;
  float m_run = -3.0e38f;            // per-ROW running max (row = cl)
  float l_run = 0.f;                 // per-lane partial, scale 2^-m_run
  int krow = t >> 2, koff = (t & 3) * 8;
  const f16* kaSrc = Ka + ((size_t)bh * 2048 + krow) * 32 + koff;
  const f16* ksSrc = Ks + ((size_t)bh * 2048 + krow) * 32 + koff;
  const f16* xb = xt + ((size_t)b * 256 + wv * 64) * 2048;
  float* a0p = attn0 + (size_t)b * 16384 + h * 2048;

  // prologue: stage K tile 0
  *(f16x8*)&KaL[0][krow][koff] = *(const f16x8*)kaSrc;
  *(f16x8*)&KsL[0][krow][koff] = *(const f16x8*)ksSrc;
  __syncthreads();

  for (int kt = 0; kt < 32; ++kt) {
    int buf = kt & 1;
    f16x8 kan, ksn;
    if (kt < 31) {
      kan = *(const f16x8*)(kaSrc + (size_t)(kt + 1) * 2048);
      ksn = *(const f16x8*)(ksSrc + (size_t)(kt + 1) * 2048);
    }
    // Xt B-frags straight from global (L2-resident)
    f16x8 xf[2][4];
#pragma unroll
    for (int ks2 = 0; ks2 < 2; ++ks2)
#pragma unroll
      for (int ddt = 0; ddt < 4; ++ddt)
        xf[ks2][ddt] = *(const f16x8*)(xb + (size_t)(ddt * 16 + cl) * 2048 +
                                       kt * 64 + ks2 * 32 + g * 8);
    // --- dual QK^T (S^T tiles: A=K rows j, B=Q); s in log2 domain ---
    float p[16];
    float tmax = -3.0e38f;
#pragma unroll
    for (int jt = 0; jt < 4; ++jt) {
      f16x8 kaf = *(const f16x8*)&KaL[buf][jt * 16 + cl][g * 8];
      f16x8 ksf = *(const f16x8*)&KsL[buf][jt * 16 + cl][g * 8];
      f32x4 za = __builtin_amdgcn_mfma_f32_16x16x32_f16(kaf, qaf, z4, 0, 0, 0);
      f32x4 zs = __builtin_amdgcn_mfma_f32_16x16x32_f16(ksf, qsf, z4, 0, 0, 0);
#pragma unroll
      for (int r = 0; r < 4; ++r) {
        float sv = za[r] * zs[r];          // K_aux prescaled by SCL
        p[jt * 4 + r] = sv;
        tmax = fmaxf(tmax, sv);
      }
    }
    // per-ROW max: reduce across the 4 quad-groups sharing row cl
    tmax = fmaxf(tmax, __shfl_xor(tmax, 16, 64));
    tmax = fmaxf(tmax, __shfl_xor(tmax, 32, 64));
    bool upd = tmax > m_run;
    float m_new = upd ? tmax + 6.0f : m_run;    // +6 hysteresis overshoot
    float alpha = upd ? exp2f(m_run - m_new) : 1.0f;
    // attn row 0 (output 2): store RAW scores (scale-free)
    if (qt == 0 && wv == 0 && cl == 0) {
#pragma unroll
      for (int jt = 0; jt < 4; ++jt) {
        float4 v = { p[jt * 4 + 0], p[jt * 4 + 1], p[jt * 4 + 2], p[jt * 4 + 3] };
        *(float4*)(a0p + kt * 64 + jt * 16 + g * 4) = v;
      }
    }
    float lsum = 0.f;
#pragma unroll
    for (int q = 0; q < 16; ++q) {
      p[q] = exp2f(p[q] - m_new);
      lsum += p[q];
    }
    l_run = l_run * alpha + lsum;
    m_run = m_new;
    // commit staged K(kt+1)
    if (kt < 31) {
      *(f16x8*)&KaL[buf ^ 1][krow][koff] = kan;
      *(f16x8*)&KsL[buf ^ 1][krow][koff] = ksn;
    }
    if (g == 0) alphaL[buf][wv * 16 + cl] = alpha;   // 1.0 when no update
    // P -> LDS in A-operand layout [q][j]
#pragma unroll
    for (int jt = 0; jt < 4; ++jt) {
      f16x4 pk = { (f16)p[jt * 4 + 0], (f16)p[jt * 4 + 1],
                   (f16)p[jt * 4 + 2], (f16)p[jt * 4 + 3] };
      *(f16x4*)&PL[buf][wv * 16 + cl][jt * 16 + g * 4] = pk;
    }
    __syncthreads();
    // --- alpha rescale (rare thanks to hysteresis): float4 loads + __any ---
    float4 av[4];
    int need = 0;
#pragma unroll
    for (int qt2 = 0; qt2 < 4; ++qt2) {
      av[qt2] = *(const float4*)&alphaL[buf][qt2 * 16 + g * 4];
      need |= (av[qt2].x != 1.0f) | (av[qt2].y != 1.0f) |
              (av[qt2].z != 1.0f) | (av[qt2].w != 1.0f);
    }
    if (__any(need)) {
#pragma unroll
      for (int qt2 = 0; qt2 < 4; ++qt2)
#pragma unroll
        for (int ddt = 0; ddt < 4; ++ddt) {
          acc[qt2][ddt][0] *= av[qt2].x;
          acc[qt2][ddt][1] *= av[qt2].y;
          acc[qt2][ddt][2] *= av[qt2].z;
          acc[qt2][ddt][3] *= av[qt2].w;
        }
    }
    // --- PV: O[q][dd] += P[q][j] * Xt[dd][j], wave's 64-dd slice ---
#pragma unroll
    for (int ks2 = 0; ks2 < 2; ++ks2) {
      f16x8 pf[4];
#pragma unroll
      for (int qt2 = 0; qt2 < 4; ++qt2)
        pf[qt2] = *(const f16x8*)&PL[buf][qt2 * 16 + cl][ks2 * 32 + g * 8];
#pragma unroll
      for (int ddt = 0; ddt < 4; ++ddt)
#pragma unroll
        for (int qt2 = 0; qt2 < 4; ++qt2)
          acc[qt2][ddt] = __builtin_amdgcn_mfma_f32_16x16x32_f16(
              pf[qt2], xf[ks2][ddt], acc[qt2][ddt], 0, 0, 0);
    }
  }
  // epilogue: reduce l across quad groups (m_run sequence is row-uniform,
  // so the 4 partials share the same scale)
  l_run += __shfl_xor(l_run, 16, 64);
  l_run += __shfl_xor(l_run, 32, 64);
  if (g == 0) lL[wv * 16 + cl] = l_run;
  if (qt == 0 && t == 0) { lq0[bh * 2] = l_run; lq0[bh * 2 + 1] = m_run; }
  __syncthreads();
#pragma unroll
  for (int qt2 = 0; qt2 < 4; ++qt2) {
#pragma unroll
    for (int r = 0; r < 4; ++r) {
      float linv = 1.0f / lL[qt2 * 16 + g * 4 + r];
      int q = qt * 64 + qt2 * 16 + g * 4 + r;
#pragma unroll
      for (int ddt = 0; ddt < 4; ++ddt) {
        float v = acc[qt2][ddt][r] * linv;
        int col = h * 256 + wv * 64 + ddt * 16 + cl;
        out[((size_t)b * 2048 + q) * 2048 + col] = v;
        if (q == 0) out_cls[(size_t)b * 2048 + col] = v;
      }
    }
  }
}

// ---------------- K3: normalize attn row 0 (raw s -> softmax weights) -------
__global__ __launch_bounds__(256) void k_norm0(float* __restrict__ attn0,
                                               const float* __restrict__ lq0) {
  int h = blockIdx.x, b = blockIdx.y, bh = b * 8 + h;
  float linv = 1.0f / lq0[bh * 2];
  float m0 = lq0[bh * 2 + 1];
  float* p = attn0 + (size_t)b * 16384 + h * 2048;
  int t = threadIdx.x;
#pragma unroll
  for (int r = 0; r < 8; ++r) {
    float s = p[r * 256 + t];
    p[r * 256 + t] = exp2f(s - m0) * linv;
  }
}

extern "C" void kernel_launch(void* const* d_in, const int* in_sizes, int n_in,
                              void* d_out, int out_size, void* d_ws, size_t ws_size,
                              hipStream_t stream) {
  const float* x  = (const float*)d_in[0];
  const float* af = (const float*)d_in[1];
  const float* Wq = (const float*)d_in[2];
  const float* Wa = (const float*)d_in[3];
  // ws (f16): Qs|Ks|Qa|Ka (4x1M) | xt (1M) | Wt (256K) | lq0 (32 f32)
  const size_t QK = (size_t)2 * 8 * 2048 * 32;
  f16* Qs = (f16*)d_ws;
  f16* Ks = Qs + QK;
  f16* Qa = Ks + QK;
  f16* Ka = Qa + QK;
  f16* xt = Ka + QK;
  f16* Wt = xt + QK;
  float* lq0 = (float*)(Wt + (size_t)2 * 512 * 256);
  float* out     = (float*)d_out;
  float* out_cls = out + (size_t)2 * 2048 * 2048;
  float* attn0   = out_cls + 2 * 2048;

  k_stage<<<dim3(40, 4, 2), 256, 0, stream>>>(x, Wq, Wa, xt, Wt);
  k_proj<<<dim3(64, 2, 2), 256, 0, stream>>>(x, af, Wt, Qs, Ks, Qa, Ka);
  k_flash<<<dim3(32, 8, 2), 256, 0, stream>>>(Qs, Ks, Qa, Ka, xt, out, out_cls,
                                              attn0, lq0);
  k_norm0<<<dim3(8, 2), 256, 0, stream>>>(attn0, lq0);
}

// Round 7
// 224.727 us; speedup vs baseline: 1.3672x; 1.3672x over previous
//
#include <hip/hip_runtime.h>

typedef _Float16 f16;
typedef _Float16 f16x4 __attribute__((ext_vector_type(4)));
typedef _Float16 f16x8 __attribute__((ext_vector_type(8)));
typedef float f32x4 __attribute__((ext_vector_type(4)));

#define SCL (1.4426950408889634f / 32.0f)   // SCALE^2 * log2(e), folded into K_aux

// ---------------- K0: staging transposes (x -> xt f16, W -> Wt f16) ---------
__global__ __launch_bounds__(256) void k_stage(const float* __restrict__ x,
    const float* __restrict__ Wq, const float* __restrict__ Wa,
    f16* __restrict__ xt, f16* __restrict__ Wt) {
  __shared__ f16 tile[64][65];
  int bx = blockIdx.x;
  int t = threadIdx.x, c = t & 63, rg = t >> 6;
  if (bx < 32) {
    int n0 = bx * 64, d0 = blockIdx.y * 64, b = blockIdx.z;
#pragma unroll
    for (int r = 0; r < 16; ++r) {
      int row = r * 4 + rg;
      tile[row][c] = (f16)x[((size_t)b * 2048 + n0 + row) * 256 + d0 + c];
    }
    __syncthreads();
#pragma unroll
    for (int r = 0; r < 16; ++r) {
      int drow = r * 4 + rg;
      xt[((size_t)b * 256 + d0 + drow) * 2048 + n0 + c] = tile[c][drow];
    }
  } else {
    int n0 = (bx - 32) * 64, k0 = blockIdx.y * 64, s = blockIdx.z;
    const float* W = s ? Wa : Wq;
    f16* dst = Wt + (size_t)s * 512 * 256;
#pragma unroll
    for (int r = 0; r < 16; ++r) {
      int krow = r * 4 + rg;
      tile[krow][c] = (f16)W[(size_t)(k0 + krow) * 768 + n0 + c];
    }
    __syncthreads();
#pragma unroll
    for (int r = 0; r < 16; ++r) {
      int nrow = r * 4 + rg;
      dst[(size_t)(n0 + nrow) * 256 + k0 + c] = tile[c][nrow];
    }
  }
}

// ---------------- K1: Q/K projections (A regs reused across 4 n-tiles) ------
// Out: Q*/K* as [b*8+h][2048][32] f16.  K_aux is prescaled by SCL.
// Grid (64 m-tiles, 2 n-halves, 2 streams) = 256 blocks -> every CU busy.
__global__ __launch_bounds__(256) void k_proj(const float* __restrict__ x,
    const float* __restrict__ af, const f16* __restrict__ Wt,
    f16* __restrict__ Qs, f16* __restrict__ Ks,
    f16* __restrict__ Qa, f16* __restrict__ Ka) {
  int mt = blockIdx.x, ny = blockIdx.y, s = blockIdx.z;
  const float* A = s ? af : x;
  const f16* W = Wt + (size_t)s * 512 * 256;
  f16* Qd = s ? Qa : Qs;
  f16* Kd = s ? Ka : Ks;
  int t = threadIdx.x, wv = t >> 6, ln = t & 63, cl = ln & 15, g = ln >> 4;
  int m0 = mt * 64;
  const float* arow = A + (size_t)(m0 + wv * 16 + cl) * 256 + g * 8;
  f16x8 a[8];
#pragma unroll
  for (int k32 = 0; k32 < 8; ++k32) {
    float4 u = *(const float4*)(arow + k32 * 32);
    float4 v = *(const float4*)(arow + k32 * 32 + 4);
    a[k32] = (f16x8){ (f16)u.x, (f16)u.y, (f16)u.z, (f16)u.w,
                      (f16)v.x, (f16)v.y, (f16)v.z, (f16)v.w };
  }
  f32x4 z4 = {0.f, 0.f, 0.f, 0.f};
#pragma unroll 1
  for (int nt = 0; nt < 4; ++nt) {
    int n0 = (ny * 4 + nt) * 64;
    f32x4 acc[4] = {z4, z4, z4, z4};
    const f16* wb = W + (size_t)n0 * 256 + g * 8;
#pragma unroll
    for (int k32 = 0; k32 < 8; ++k32)
#pragma unroll
      for (int n4 = 0; n4 < 4; ++n4) {
        f16x8 bf = *(const f16x8*)(wb + (size_t)(n4 * 16 + cl) * 256 + k32 * 32);
        acc[n4] = __builtin_amdgcn_mfma_f32_16x16x32_f16(a[k32], bf, acc[n4], 0, 0, 0);
      }
#pragma unroll
    for (int n4 = 0; n4 < 4; ++n4) {
      int c = n0 + n4 * 16 + cl;             // 0..511 (Q: 0-255, K: 256-511)
      int head = (c & 255) >> 5, d = c & 31;
      f16* dst = (c < 256) ? Qd : Kd;
      float osc = (s && (n0 + n4 * 16) >= 256) ? SCL : 1.0f;  // prescale K_aux
#pragma unroll
      for (int r = 0; r < 4; ++r) {
        int m = m0 + wv * 16 + g * 4 + r;
        int bb = m >> 11, nn = m & 2047;
        dst[(((size_t)bb * 8 + head) * 2048 + nn) * 32 + d] = (f16)(acc[n4][r] * osc);
      }
    }
  }
}

// ---------------- K2: fused dual-score flash attention ----------------------
// EXACT round-2 structure (proven 92 us @ 128 VGPR). Only change: the *SCL
// mul is gone (K_aux prescaled in k_proj). No launch_bounds 2nd arg — 132
// VGPR (r5) halved MfmaUtil; (256,4) (r6) spilled to scratch at 4x traffic.
__global__ __launch_bounds__(256) void k_flash(const f16* __restrict__ Qs,
    const f16* __restrict__ Ks, const f16* __restrict__ Qa,
    const f16* __restrict__ Ka, const f16* __restrict__ xt,
    float* __restrict__ out, float* __restrict__ out_cls) {
  __shared__ f16 KaL[2][64][40];     // pitch 80B
  __shared__ f16 KsL[2][64][40];
  __shared__ f16 PL[2][64][72];      // [q][j], pitch 144B
  __shared__ float alphaL[2][64];
  __shared__ float lL[64];
  int qt = blockIdx.x, h = blockIdx.y, b = blockIdx.z;
  int bh = b * 8 + h;
  int t = threadIdx.x, wv = t >> 6, ln = t & 63, cl = ln & 15, g = ln >> 4;
  int qrow0 = qt * 64 + wv * 16;
  f16x8 qsf = *(const f16x8*)&Qs[((size_t)bh * 2048 + qrow0 + cl) * 32 + g * 8];
  f16x8 qaf = *(const f16x8*)&Qa[((size_t)bh * 2048 + qrow0 + cl) * 32 + g * 8];
  f32x4 z4 = {0.f, 0.f, 0.f, 0.f};
  f32x4 acc[4][4];                   // [qt2][ddt]
#pragma unroll
  for (int i = 0; i < 4; ++i)
#pragma unroll
    for (int j = 0; j < 4; ++j) acc[i][j] = z4;
  float m_run = -3.0e38f;            // per-ROW running max (row = cl)
  float l_run = 0.f;
  int krow = t >> 2, koff = (t & 3) * 8;
  const f16* kaSrc = Ka + ((size_t)bh * 2048 + krow) * 32 + koff;
  const f16* ksSrc = Ks + ((size_t)bh * 2048 + krow) * 32 + koff;
  const f16* xb = xt + ((size_t)b * 256 + wv * 64) * 2048;

  // prologue: stage K tile 0
  *(f16x8*)&KaL[0][krow][koff] = *(const f16x8*)kaSrc;
  *(f16x8*)&KsL[0][krow][koff] = *(const f16x8*)ksSrc;
  __syncthreads();

  for (int kt = 0; kt < 32; ++kt) {
    int buf = kt & 1;
    f16x8 kan, ksn;
    if (kt < 31) {
      kan = *(const f16x8*)(kaSrc + (size_t)(kt + 1) * 2048);
      ksn = *(const f16x8*)(ksSrc + (size_t)(kt + 1) * 2048);
    }
    // Xt B-frags straight from global (L2-resident)
    f16x8 xf[2][4];
#pragma unroll
    for (int ks2 = 0; ks2 < 2; ++ks2)
#pragma unroll
      for (int ddt = 0; ddt < 4; ++ddt)
        xf[ks2][ddt] = *(const f16x8*)(xb + (size_t)(ddt * 16 + cl) * 2048 +
                                       kt * 64 + ks2 * 32 + g * 8);
    // --- dual QK^T (S^T tiles: A=K rows j, B=Q); s in log2 domain ---
    float p[16];
    float tmax = -3.0e38f;
#pragma unroll
    for (int jt = 0; jt < 4; ++jt) {
      f16x8 kaf = *(const f16x8*)&KaL[buf][jt * 16 + cl][g * 8];
      f16x8 ksf = *(const f16x8*)&KsL[buf][jt * 16 + cl][g * 8];
      f32x4 za = __builtin_amdgcn_mfma_f32_16x16x32_f16(kaf, qaf, z4, 0, 0, 0);
      f32x4 zs = __builtin_amdgcn_mfma_f32_16x16x32_f16(ksf, qsf, z4, 0, 0, 0);
#pragma unroll
      for (int r = 0; r < 4; ++r) {
        float sv = za[r] * zs[r];          // K_aux prescaled by SCL
        p[jt * 4 + r] = sv;
        tmax = fmaxf(tmax, sv);
      }
    }
    tmax = fmaxf(tmax, __shfl_xor(tmax, 16, 64));
    tmax = fmaxf(tmax, __shfl_xor(tmax, 32, 64));
    float m_new = fmaxf(m_run, tmax);
    float alpha = exp2f(m_run - m_new);    // 1.0 exactly when max unchanged
    float lsum = 0.f;
#pragma unroll
    for (int q = 0; q < 16; ++q) {
      p[q] = exp2f(p[q] - m_new);
      lsum += p[q];
    }
    lsum += __shfl_xor(lsum, 16, 64);
    lsum += __shfl_xor(lsum, 32, 64);
    l_run = l_run * alpha + lsum;
    m_run = m_new;
    // commit staged K(kt+1)
    if (kt < 31) {
      *(f16x8*)&KaL[buf ^ 1][krow][koff] = kan;
      *(f16x8*)&KsL[buf ^ 1][krow][koff] = ksn;
    }
    if (g == 0) alphaL[buf][wv * 16 + cl] = alpha;
    // P -> LDS in A-operand layout [q][j]
#pragma unroll
    for (int jt = 0; jt < 4; ++jt) {
      f16x4 pk = { (f16)p[jt * 4 + 0], (f16)p[jt * 4 + 1],
                   (f16)p[jt * 4 + 2], (f16)p[jt * 4 + 3] };
      *(f16x4*)&PL[buf][wv * 16 + cl][jt * 16 + g * 4] = pk;
    }
    __syncthreads();
    // --- alpha rescale: skipped when no row max moved (common path) ---
    float av[4][4];
    int need = 0;
#pragma unroll
    for (int qt2 = 0; qt2 < 4; ++qt2)
#pragma unroll
      for (int r = 0; r < 4; ++r) {
        float a = alphaL[buf][qt2 * 16 + g * 4 + r];
        av[qt2][r] = a;
        need |= (a != 1.0f);
      }
    if (__any(need)) {
#pragma unroll
      for (int qt2 = 0; qt2 < 4; ++qt2)
#pragma unroll
        for (int ddt = 0; ddt < 4; ++ddt)
#pragma unroll
          for (int r = 0; r < 4; ++r) acc[qt2][ddt][r] *= av[qt2][r];
    }
    // --- PV: O[q][dd] += P[q][j] * Xt[dd][j], wave's 64-dd slice ---
#pragma unroll
    for (int ks2 = 0; ks2 < 2; ++ks2) {
      f16x8 pf[4];
#pragma unroll
      for (int qt2 = 0; qt2 < 4; ++qt2)
        pf[qt2] = *(const f16x8*)&PL[buf][qt2 * 16 + cl][ks2 * 32 + g * 8];
#pragma unroll
      for (int ddt = 0; ddt < 4; ++ddt)
#pragma unroll
        for (int qt2 = 0; qt2 < 4; ++qt2)
          acc[qt2][ddt] = __builtin_amdgcn_mfma_f32_16x16x32_f16(
              pf[qt2], xf[ks2][ddt], acc[qt2][ddt], 0, 0, 0);
    }
  }
  // epilogue
  if (g == 0) lL[wv * 16 + cl] = l_run;
  __syncthreads();
#pragma unroll
  for (int qt2 = 0; qt2 < 4; ++qt2) {
#pragma unroll
    for (int r = 0; r < 4; ++r) {
      float linv = 1.0f / lL[qt2 * 16 + g * 4 + r];
      int q = qt * 64 + qt2 * 16 + g * 4 + r;
#pragma unroll
      for (int ddt = 0; ddt < 4; ++ddt) {
        float v = acc[qt2][ddt][r] * linv;
        int col = h * 256 + wv * 64 + ddt * 16 + cl;
        out[((size_t)b * 2048 + q) * 2048 + col] = v;
        if (q == 0) out_cls[(size_t)b * 2048 + col] = v;
      }
    }
  }
}

// ---------------- K3: attn probs for query row 0, fused normalize -----------
// 1024 threads (16 waves) per (b,h): each thread computes 2 scores, two-level
// reduction (wave shfl + LDS), writes normalized weights. Ka prescaled -> s
// is already in log2 domain.
__global__ __launch_bounds__(1024) void k_attn0(const f16* __restrict__ Qs,
    const f16* __restrict__ Ks, const f16* __restrict__ Qa,
    const f16* __restrict__ Ka, float* __restrict__ dst) {
  __shared__ float qa_s[32], qs_s[32];
  __shared__ float redm[16], redl[16];
  int h = blockIdx.x, b = blockIdx.y, bh = b * 8 + h;
  int t = threadIdx.x, wv = t >> 6, ln = t & 63;
  if (t < 32) {
    qa_s[t] = (float)Qa[(size_t)bh * 2048 * 32 + t];
    qs_s[t] = (float)Qs[(size_t)bh * 2048 * 32 + t];
  }
  __syncthreads();
  float s[2];
#pragma unroll
  for (int jj = 0; jj < 2; ++jj) {
    int j = jj * 1024 + t;
    const f16x8* ka8 = (const f16x8*)&Ka[((size_t)bh * 2048 + j) * 32];
    const f16x8* ks8 = (const f16x8*)&Ks[((size_t)bh * 2048 + j) * 32];
    float da = 0.f, ds = 0.f;
#pragma unroll
    for (int c = 0; c < 4; ++c) {
      f16x8 va = ka8[c], vs = ks8[c];
#pragma unroll
      for (int d = 0; d < 8; ++d) {
        da += qa_s[c * 8 + d] * (float)va[d];
        ds += qs_s[c * 8 + d] * (float)vs[d];
      }
    }
    s[jj] = da * ds;                 // log2 domain (Ka prescaled)
  }
  // max: wave-level then cross-wave
  float mx = fmaxf(s[0], s[1]);
#pragma unroll
  for (int off = 1; off < 64; off <<= 1)
    mx = fmaxf(mx, __shfl_xor(mx, off, 64));
  if (ln == 0) redm[wv] = mx;
  __syncthreads();
  float m = redm[0];
#pragma unroll
  for (int w = 1; w < 16; ++w) m = fmaxf(m, redm[w]);
  // exp + sum
  float e0 = exp2f(s[0] - m), e1 = exp2f(s[1] - m);
  float ls = e0 + e1;
#pragma unroll
  for (int off = 1; off < 64; off <<= 1)
    ls += __shfl_xor(ls, off, 64);
  if (ln == 0) redl[wv] = ls;
  __syncthreads();
  float l = 0.f;
#pragma unroll
  for (int w = 0; w < 16; ++w) l += redl[w];
  float linv = 1.0f / l;
  float* p = dst + (size_t)b * 16384 + h * 2048;
  p[t] = e0 * linv;
  p[1024 + t] = e1 * linv;
}

extern "C" void kernel_launch(void* const* d_in, const int* in_sizes, int n_in,
                              void* d_out, int out_size, void* d_ws, size_t ws_size,
                              hipStream_t stream) {
  const float* x  = (const float*)d_in[0];
  const float* af = (const float*)d_in[1];
  const float* Wq = (const float*)d_in[2];
  const float* Wa = (const float*)d_in[3];
  // ws (f16): Qs|Ks|Qa|Ka (4x1M) | xt (1M) | Wt (256K)
  const size_t QK = (size_t)2 * 8 * 2048 * 32;
  f16* Qs = (f16*)d_ws;
  f16* Ks = Qs + QK;
  f16* Qa = Ks + QK;
  f16* Ka = Qa + QK;
  f16* xt = Ka + QK;
  f16* Wt = xt + QK;
  float* out     = (float*)d_out;
  float* out_cls = out + (size_t)2 * 2048 * 2048;
  float* attn0   = out_cls + 2 * 2048;

  k_stage<<<dim3(40, 4, 2), 256, 0, stream>>>(x, Wq, Wa, xt, Wt);
  k_proj<<<dim3(64, 2, 2), 256, 0, stream>>>(x, af, Wt, Qs, Ks, Qa, Ka);
  k_flash<<<dim3(32, 8, 2), 256, 0, stream>>>(Qs, Ks, Qa, Ka, xt, out, out_cls);
  k_attn0<<<dim3(8, 2), 1024, 0, stream>>>(Qs, Ks, Qa, Ka, attn0);
}